// Round 3
// baseline (10303.662 us; speedup 1.0000x reference)
//
#include <hip/hip_runtime.h>
#include <math.h>

#define TT_ 128
#define DD 64
#define HH 256
#define BB 16      // batch rows per block (MFMA M-tile)
#define NBLK 64    // 1024/16
#define NTHR 512   // 8 waves

// LDS strides (f32 elements), odd multiples of 16B to spread banks.
#define SA 260
#define SX 68
#define SG 516

typedef short bf16x8 __attribute__((ext_vector_type(8)));
typedef float f32x4 __attribute__((ext_vector_type(4)));
typedef unsigned int uint;
typedef unsigned short ushort;
typedef uint u32x4 __attribute__((ext_vector_type(4)));

// ---- fragment-linear packed weights (bf16 hi/lo pairs), written by prep ----
// layout [tile][koct][term][lane*8+j] ; frag elem = W[t*16 + l%16][o*32 + (l/16)*8 + j]
__device__ ushort g_W1p[16 * 8 * 2 * 512];    // W1  (256x256)
__device__ ushort g_W2p[16 * 8 * 2 * 512];    // W2  (256x256)
__device__ ushort g_Wrzp[32 * 10 * 2 * 512];  // [Whh rows 0..511 | Wih rows 0..511]
__device__ ushort g_Whnp[16 * 8 * 2 * 512];   // Whh rows 512..767
__device__ ushort g_Winp[16 * 2 * 512];       // Wih rows 512..767 (hi only)

__device__ __forceinline__ ushort bf16_rne(float f) {
  uint u = __builtin_bit_cast(uint, f);
  return (ushort)((u + 0x7fffu + ((u >> 16) & 1u)) >> 16);
}
__device__ __forceinline__ float bf16_f32(ushort h) {
  uint u = ((uint)h) << 16;
  return __builtin_bit_cast(float, u);
}

__global__ __launch_bounds__(256) void prep(
    const float* __restrict__ W1, const float* __restrict__ W2,
    const float* __restrict__ Wih, const float* __restrict__ Whh)
{
  const int s = blockIdx.x * 256 + threadIdx.x;
  const int S1 = 16 * 8 * 512;
  const int S2 = S1 + 16 * 8 * 512;
  const int S3 = S2 + 32 * 10 * 512;
  const int S4 = S3 + 16 * 8 * 512;
  const int S5 = S4 + 16 * 2 * 512;
  if (s >= S5) return;

  if (s < S2) {  // W1 / W2
    const int r = (s < S1) ? s : s - S1;
    const int t = r / (8 * 512);
    const int o = (r / 512) & 7;
    const int pos = r & 511;
    const int l = pos >> 3, j = pos & 7;
    const int n = t * 16 + (l & 15);
    const int k = o * 32 + (l >> 4) * 8 + j;
    const float w = (s < S1) ? W1[n * HH + k] : W2[n * HH + k];
    ushort hi = bf16_rne(w);
    ushort lo = bf16_rne(w - bf16_f32(hi));
    ushort* dst = (s < S1) ? g_W1p : g_W2p;
    dst[((t * 8 + o) * 2) * 512 + pos] = hi;
    dst[((t * 8 + o) * 2 + 1) * 512 + pos] = lo;
  } else if (s < S3) {  // Wrz
    const int r = s - S2;
    const int t = r / (10 * 512);
    const int o = (r / 512) % 10;
    const int pos = r & 511;
    const int l = pos >> 3, j = pos & 7;
    const int n = t * 16 + (l & 15);
    float w;
    if (o < 8) w = Whh[n * HH + o * 32 + (l >> 4) * 8 + j];
    else       w = Wih[n * DD + (o - 8) * 32 + (l >> 4) * 8 + j];
    ushort hi = bf16_rne(w);
    ushort lo = bf16_rne(w - bf16_f32(hi));
    g_Wrzp[((t * 10 + o) * 2) * 512 + pos] = hi;
    g_Wrzp[((t * 10 + o) * 2 + 1) * 512 + pos] = lo;
  } else if (s < S4) {  // Whn
    const int r = s - S3;
    const int t = r / (8 * 512);
    const int o = (r / 512) & 7;
    const int pos = r & 511;
    const int l = pos >> 3, j = pos & 7;
    const int n = 512 + t * 16 + (l & 15);
    const float w = Whh[n * HH + o * 32 + (l >> 4) * 8 + j];
    ushort hi = bf16_rne(w);
    ushort lo = bf16_rne(w - bf16_f32(hi));
    g_Whnp[((t * 8 + o) * 2) * 512 + pos] = hi;
    g_Whnp[((t * 8 + o) * 2 + 1) * 512 + pos] = lo;
  } else {  // Win (hi only)
    const int r = s - S4;
    const int t = r / (2 * 512);
    const int o = (r / 512) & 1;
    const int pos = r & 511;
    const int l = pos >> 3, j = pos & 7;
    const int n = 512 + t * 16 + (l & 15);
    const float w = Wih[n * DD + o * 32 + (l >> 4) * 8 + j];
    g_Winp[(t * 2 + o) * 512 + pos] = bf16_rne(w);
  }
}

// Build A hi/lo bf16x8 fragments from 8 consecutive f32 in LDS.
__device__ __forceinline__ void build_frags(const float* __restrict__ ap,
                                            bf16x8& ahi, bf16x8& alo)
{
  const float4 a0 = *(const float4*)ap;
  const float4 a1 = *(const float4*)(ap + 4);
  float af[8] = {a0.x, a0.y, a0.z, a0.w, a1.x, a1.y, a1.z, a1.w};
  uint hu[4], lu[4];
#pragma unroll
  for (int jj = 0; jj < 4; ++jj) {
    const uint ue = __builtin_bit_cast(uint, af[2 * jj]);
    const uint uo = __builtin_bit_cast(uint, af[2 * jj + 1]);
    hu[jj] = (ue >> 16) | (uo & 0xffff0000u);
    const float he = __builtin_bit_cast(float, ue & 0xffff0000u);
    const float ho = __builtin_bit_cast(float, uo & 0xffff0000u);
    const uint le = __builtin_bit_cast(uint, af[2 * jj] - he);
    const uint lo = __builtin_bit_cast(uint, af[2 * jj + 1] - ho);
    lu[jj] = (le >> 16) | (lo & 0xffff0000u);
  }
  u32x4 hv = {hu[0], hu[1], hu[2], hu[3]};
  u32x4 lv = {lu[0], lu[1], lu[2], lu[3]};
  ahi = __builtin_bit_cast(bf16x8, hv);
  alo = __builtin_bit_cast(bf16x8, lv);
}

#define MFMA(A, B, C) __builtin_amdgcn_mfma_f32_16x16x32_bf16((A), (B), (C), 0, 0, 0)

// 2 N-tiles, K=256, 3-term. Full-stage prefetch: issue ALL weight loads,
// then build all A-frags from LDS (covers load latency), then MFMA.
__device__ __forceinline__ void mm2t3(const float* __restrict__ src, int stride,
                                      const ushort* __restrict__ pack, int t0,
                                      int lane, f32x4& acc0, f32x4& acc1)
{
  const int l15 = lane & 15, lq = lane >> 4;
  const ushort* pb = pack + lane * 8;
  bf16x8 w[32];
#pragma unroll
  for (int o = 0; o < 8; ++o) {
    const ushort* p0 = pb + ((t0 * 8 + o) * 2) * 512;
    const ushort* p1 = pb + (((t0 + 1) * 8 + o) * 2) * 512;
    w[4 * o + 0] = *(const bf16x8*)p0;
    w[4 * o + 1] = *(const bf16x8*)(p0 + 512);
    w[4 * o + 2] = *(const bf16x8*)p1;
    w[4 * o + 3] = *(const bf16x8*)(p1 + 512);
  }
  bf16x8 ah[8], al[8];
#pragma unroll
  for (int o = 0; o < 8; ++o)
    build_frags(src + l15 * stride + o * 32 + lq * 8, ah[o], al[o]);
#pragma unroll
  for (int o = 0; o < 8; ++o) {
    acc0 = MFMA(ah[o], w[4 * o + 0], acc0);
    acc1 = MFMA(ah[o], w[4 * o + 2], acc1);
    acc0 = MFMA(al[o], w[4 * o + 0], acc0);
    acc1 = MFMA(al[o], w[4 * o + 2], acc1);
    acc0 = MFMA(ah[o], w[4 * o + 1], acc0);
    acc1 = MFMA(ah[o], w[4 * o + 3], acc1);
  }
}

// GRU r,z matmul for tile pair (t0, t0+1): K=256 h-part (3-term) + K=64 x-part (2-term)
__device__ __forceinline__ void mm_rz_pair(const float* __restrict__ hsrc,
                                           const float* __restrict__ xsrc,
                                           int lane, int t0,
                                           f32x4& az0, f32x4& az1)
{
  const int l15 = lane & 15, lq = lane >> 4;
  const ushort* pb = g_Wrzp + lane * 8;
  bf16x8 w[32], wx[4];
#pragma unroll
  for (int o = 0; o < 8; ++o) {
    const ushort* p0 = pb + ((t0 * 10 + o) * 2) * 512;
    const ushort* p1 = pb + (((t0 + 1) * 10 + o) * 2) * 512;
    w[4 * o + 0] = *(const bf16x8*)p0;
    w[4 * o + 1] = *(const bf16x8*)(p0 + 512);
    w[4 * o + 2] = *(const bf16x8*)p1;
    w[4 * o + 3] = *(const bf16x8*)(p1 + 512);
  }
#pragma unroll
  for (int o = 0; o < 2; ++o) {
    wx[2 * o + 0] = *(const bf16x8*)(pb + ((t0 * 10 + 8 + o) * 2) * 512);
    wx[2 * o + 1] = *(const bf16x8*)(pb + (((t0 + 1) * 10 + 8 + o) * 2) * 512);
  }
  bf16x8 xh[2], xl[2];
#pragma unroll
  for (int o = 0; o < 2; ++o)
    build_frags(xsrc + l15 * SX + o * 32 + lq * 8, xh[o], xl[o]);
#pragma unroll
  for (int o = 0; o < 2; ++o) {
    az0 = MFMA(xh[o], wx[2 * o + 0], az0);
    az0 = MFMA(xl[o], wx[2 * o + 0], az0);
    az1 = MFMA(xh[o], wx[2 * o + 1], az1);
    az1 = MFMA(xl[o], wx[2 * o + 1], az1);
  }
  bf16x8 ah[8], al[8];
#pragma unroll
  for (int o = 0; o < 8; ++o)
    build_frags(hsrc + l15 * SA + o * 32 + lq * 8, ah[o], al[o]);
#pragma unroll
  for (int o = 0; o < 8; ++o) {
    az0 = MFMA(ah[o], w[4 * o + 0], az0);
    az1 = MFMA(ah[o], w[4 * o + 2], az1);
    az0 = MFMA(al[o], w[4 * o + 0], az0);
    az1 = MFMA(al[o], w[4 * o + 2], az1);
    az0 = MFMA(ah[o], w[4 * o + 1], az0);
    az1 = MFMA(ah[o], w[4 * o + 3], az1);
  }
}

// GRU n-gate x-side: 2 tiles, K=64, hi-only weights, 2-term
__device__ __forceinline__ void mm_in_f(const float* __restrict__ xsrc,
                                        int lane, int t0, f32x4& acc0, f32x4& acc1)
{
  const int l15 = lane & 15, lq = lane >> 4;
  bf16x8 wv[4];
#pragma unroll
  for (int o = 0; o < 2; ++o) {
    wv[2 * o + 0] = *(const bf16x8*)(g_Winp + (t0 * 2 + o) * 512 + lane * 8);
    wv[2 * o + 1] = *(const bf16x8*)(g_Winp + ((t0 + 1) * 2 + o) * 512 + lane * 8);
  }
  bf16x8 xh[2], xl[2];
#pragma unroll
  for (int o = 0; o < 2; ++o)
    build_frags(xsrc + l15 * SX + o * 32 + lq * 8, xh[o], xl[o]);
#pragma unroll
  for (int o = 0; o < 2; ++o) {
    acc0 = MFMA(xh[o], wv[2 * o + 0], acc0);
    acc0 = MFMA(xl[o], wv[2 * o + 0], acc0);
    acc1 = MFMA(xh[o], wv[2 * o + 1], acc1);
    acc1 = MFMA(xl[o], wv[2 * o + 1], acc1);
  }
}

__global__ __launch_bounds__(NTHR, 2) void odegru_kernel(
    const float* __restrict__ x, const float* __restrict__ times,
    const float* __restrict__ mask,
    const float* __restrict__ b1, const float* __restrict__ b2,
    const float* __restrict__ bih, const float* __restrict__ bhh,
    float* __restrict__ out)
{
  __shared__ __align__(16) float sAh[BB * SA];
  __shared__ __align__(16) float sAin[BB * SA];
  __shared__ __align__(16) float sU[BB * SA];
  __shared__ __align__(16) float sX[BB * SX];
  __shared__ __align__(16) float sGRZ[BB * SG];
  __shared__ __align__(16) float sGHN[BB * SA];
  __shared__ __align__(16) float sGIN[BB * SA];

  const int tid = threadIdx.x;
  const int lane = tid & 63;
  const int w = tid >> 6;
  const int l15 = lane & 15;
  const int lq = lane >> 4;
  const int b0 = blockIdx.x * BB;

  const int c0 = (2 * w) * 16 + l15;
  const int c1 = (2 * w + 1) * 16 + l15;
  const float b1c0 = b1[c0], b1c1 = b1[c1];
  const float b2c0 = b2[c0], b2c1 = b2[c1];

  const int pi = tid & 255;
  const int pb0 = (tid >> 8) * 8;
  const float brz_r = bih[pi] + bhh[pi];
  const float brz_z = bih[pi + 256] + bhh[pi + 256];
  const float bn_i = bih[pi + 512];
  const float bn_h = bhh[pi + 512];

  const f32x4 Z = {0.f, 0.f, 0.f, 0.f};

  auto feval = [&](const float* src, f32x4& kv0, f32x4& kv1) {
    f32x4 a0 = Z, a1 = Z;
    mm2t3(src, SA, g_W1p, 2 * w, lane, a0, a1);
#pragma unroll
    for (int r = 0; r < 4; ++r) {
      const int b = lq * 4 + r;
      sU[b * SA + c0] = fmaxf(a0[r] + b1c0, 0.f);
      sU[b * SA + c1] = fmaxf(a1[r] + b1c1, 0.f);
    }
    __syncthreads();
    f32x4 p0 = Z, p1 = Z;
    mm2t3(sU, SA, g_W2p, 2 * w, lane, p0, p1);
    kv0 = p0 + b2c0;
    kv1 = p1 + b2c1;
  };

  auto wAin = [&](float coef, const f32x4& v0, const f32x4& v1) {
#pragma unroll
    for (int r = 0; r < 4; ++r) {
      const int b = lq * 4 + r;
      sAin[b * SA + c0] = sAh[b * SA + c0] + coef * v0[r];
      sAin[b * SA + c1] = sAh[b * SA + c1] + coef * v1[r];
    }
  };

  for (int t = 0; t < TT_; ++t) {
    {
      const int b = tid >> 5, d = (tid & 31) * 2;
      const float2 v = *(const float2*)&x[((size_t)(b0 + b) * TT_ + t) * DD + d];
      sX[b * SX + d] = v.x;
      sX[b * SX + d + 1] = v.y;
    }
    if (t == 0) {
#pragma unroll
      for (int q = 0; q < 8; ++q) {
        const int idx = tid * 8 + q;
        sAin[(idx >> 8) * SA + (idx & 255)] = 0.f;
      }
    }
    __syncthreads();

    if (t > 0) {
      const float dtv = times[t] - times[t - 1];
      f32x4 kv0, kv1, ks0, ks1;
      feval(sAh, kv0, kv1);
      ks0 = kv0; ks1 = kv1;
      wAin(0.5f * dtv, kv0, kv1);
      __syncthreads();
      feval(sAin, kv0, kv1);
      ks0 += 2.0f * kv0; ks1 += 2.0f * kv1;
      wAin(0.5f * dtv, kv0, kv1);
      __syncthreads();
      feval(sAin, kv0, kv1);
      ks0 += 2.0f * kv0; ks1 += 2.0f * kv1;
      wAin(dtv, kv0, kv1);
      __syncthreads();
      feval(sAin, kv0, kv1);
      ks0 += kv0; ks1 += kv1;
      wAin(dtv * (1.0f / 6.0f), ks0, ks1);
      __syncthreads();
    }

    // ---- GRU matmuls (read sAin, sX) ----
    {
      f32x4 az0 = Z, az1 = Z, az2 = Z, az3 = Z;
      mm_rz_pair(sAin, sX, lane, 4 * w, az0, az1);
      mm_rz_pair(sAin, sX, lane, 4 * w + 2, az2, az3);
#pragma unroll
      for (int r = 0; r < 4; ++r) {
        const int b = lq * 4 + r;
        sGRZ[b * SG + (4 * w + 0) * 16 + l15] = az0[r];
        sGRZ[b * SG + (4 * w + 1) * 16 + l15] = az1[r];
        sGRZ[b * SG + (4 * w + 2) * 16 + l15] = az2[r];
        sGRZ[b * SG + (4 * w + 3) * 16 + l15] = az3[r];
      }
      f32x4 h0 = Z, h1 = Z;
      mm2t3(sAin, SA, g_Whnp, 2 * w, lane, h0, h1);
      f32x4 i0 = Z, i1 = Z;
      mm_in_f(sX, lane, 2 * w, i0, i1);
#pragma unroll
      for (int r = 0; r < 4; ++r) {
        const int b = lq * 4 + r;
        sGHN[b * SA + c0] = h0[r];
        sGHN[b * SA + c1] = h1[r];
        sGIN[b * SA + c0] = i0[r];
        sGIN[b * SA + c1] = i1[r];
      }
    }
    __syncthreads();

    // ---- GRU pointwise ----
#pragma unroll
    for (int bb = 0; bb < 8; ++bb) {
      const int b = pb0 + bb;
      const float gr = sGRZ[b * SG + pi] + brz_r;
      const float gz = sGRZ[b * SG + pi + 256] + brz_z;
      const float hn = sGHN[b * SA + pi] + bn_h;
      const float gn = sGIN[b * SA + pi] + bn_i;
      const float hode = sAin[b * SA + pi];
      const float rg = 1.f / (1.f + __expf(-gr));
      const float zg = 1.f / (1.f + __expf(-gz));
      const float ng = 1.f - 2.f / (__expf(2.f * (gn + rg * hn)) + 1.f);
      const float hnext = (1.f - zg) * ng + zg * hode;
      const float m = mask[(size_t)(b0 + b) * TT_ + t];
      const float hnew = m * hnext + (1.f - m) * hode;
      sAh[b * SA + pi] = hnew;
      out[((size_t)(b0 + b) * TT_ + t) * HH + pi] = hnew;
    }
    __syncthreads();
  }
}

extern "C" void kernel_launch(void* const* d_in, const int* in_sizes, int n_in,
                              void* d_out, int out_size, void* d_ws, size_t ws_size,
                              hipStream_t stream) {
  (void)in_sizes; (void)n_in; (void)d_ws; (void)ws_size; (void)out_size;
  const float* x     = (const float*)d_in[0];
  const float* times = (const float*)d_in[1];
  const float* mask  = (const float*)d_in[2];
  const float* W1    = (const float*)d_in[3];
  const float* b1    = (const float*)d_in[4];
  const float* W2    = (const float*)d_in[5];
  const float* b2    = (const float*)d_in[6];
  const float* Wih   = (const float*)d_in[7];
  const float* bih   = (const float*)d_in[8];
  const float* Whh   = (const float*)d_in[9];
  const float* bhh   = (const float*)d_in[10];
  float* out = (float*)d_out;

  hipLaunchKernelGGL(prep, dim3((376832 + 255) / 256), dim3(256), 0, stream,
                     W1, W2, Wih, Whh);
  hipLaunchKernelGGL(odegru_kernel, dim3(NBLK), dim3(NTHR), 0, stream,
                     x, times, mask, b1, b2, bih, bhh, out);
}

// Round 4
// 6857.893 us; speedup vs baseline: 1.5025x; 1.5025x over previous
//
#include <hip/hip_runtime.h>
#include <math.h>

#define TT_ 128
#define DD 64
#define HH 256
#define BB 16      // batch rows per block (MFMA M-tile)
#define NBLK 64    // 1024/16
#define NTHR 1024  // 16 waves, 1 N-tile (16 cols) per wave

// f32 LDS stride (elements): 260*4B = 1040B (odd multiple of 16B)
#define SA 260
// bf16 plane strides (elements): 264*2B = 528B, 72*2B = 144B (odd multiples of 16B)
#define SB 264
#define SXB 72

typedef short bf16x8 __attribute__((ext_vector_type(8)));
typedef float f32x4 __attribute__((ext_vector_type(4)));
typedef unsigned int uint;
typedef unsigned short ushort;

// ---- fragment-linear packed weights (bf16 hi/lo pairs), written by prep ----
// frag elem (tile t, oct o): W[t*16 + l%16][o*32 + (l/16)*8 + j], hi at +0, lo at +512
__device__ ushort g_W1p[16 * 8 * 2 * 512];    // W1  (256x256): t*8192 + o*1024
__device__ ushort g_W2p[16 * 8 * 2 * 512];    // W2  (256x256)
__device__ ushort g_Wrzp[32 * 10 * 2 * 512];  // Whh rows 0..511 (o<8) | Wih rows 0..511 (o=8,9): t*10240 + o*1024
__device__ ushort g_Whnp[16 * 8 * 2 * 512];   // Whh rows 512..767
__device__ ushort g_Winp[16 * 2 * 512];       // Wih rows 512..767 (hi only): t*1024 + o*512

__device__ __forceinline__ ushort bf16_rne(float f) {
  uint u = __builtin_bit_cast(uint, f);
  return (ushort)((u + 0x7fffu + ((u >> 16) & 1u)) >> 16);
}
__device__ __forceinline__ float bf16_f32(ushort h) {
  uint u = ((uint)h) << 16;
  return __builtin_bit_cast(float, u);
}
// truncation split: hi+lo reproduces f to ~2^-17 rel; same split as validated R2 kernel
__device__ __forceinline__ void hl_split(float f, ushort& hi, ushort& lo) {
  const uint u = __builtin_bit_cast(uint, f);
  hi = (ushort)(u >> 16);
  const float fh = __builtin_bit_cast(float, u & 0xffff0000u);
  lo = (ushort)(__builtin_bit_cast(uint, f - fh) >> 16);
}

__global__ __launch_bounds__(256) void prep(
    const float* __restrict__ W1, const float* __restrict__ W2,
    const float* __restrict__ Wih, const float* __restrict__ Whh)
{
  const int s = blockIdx.x * 256 + threadIdx.x;
  const int S1 = 16 * 8 * 512;
  const int S2 = S1 + 16 * 8 * 512;
  const int S3 = S2 + 32 * 10 * 512;
  const int S4 = S3 + 16 * 8 * 512;
  const int S5 = S4 + 16 * 2 * 512;
  if (s >= S5) return;

  if (s < S2) {  // W1 / W2
    const int r = (s < S1) ? s : s - S1;
    const int t = r / (8 * 512);
    const int o = (r / 512) & 7;
    const int pos = r & 511;
    const int l = pos >> 3, j = pos & 7;
    const int n = t * 16 + (l & 15);
    const int k = o * 32 + (l >> 4) * 8 + j;
    const float w = (s < S1) ? W1[n * HH + k] : W2[n * HH + k];
    ushort hi = bf16_rne(w);
    ushort lo = bf16_rne(w - bf16_f32(hi));
    ushort* dst = (s < S1) ? g_W1p : g_W2p;
    dst[((t * 8 + o) * 2) * 512 + pos] = hi;
    dst[((t * 8 + o) * 2 + 1) * 512 + pos] = lo;
  } else if (s < S3) {  // Wrz
    const int r = s - S2;
    const int t = r / (10 * 512);
    const int o = (r / 512) % 10;
    const int pos = r & 511;
    const int l = pos >> 3, j = pos & 7;
    const int n = t * 16 + (l & 15);
    float w;
    if (o < 8) w = Whh[n * HH + o * 32 + (l >> 4) * 8 + j];
    else       w = Wih[n * DD + (o - 8) * 32 + (l >> 4) * 8 + j];
    ushort hi = bf16_rne(w);
    ushort lo = bf16_rne(w - bf16_f32(hi));
    g_Wrzp[((t * 10 + o) * 2) * 512 + pos] = hi;
    g_Wrzp[((t * 10 + o) * 2 + 1) * 512 + pos] = lo;
  } else if (s < S4) {  // Whn
    const int r = s - S3;
    const int t = r / (8 * 512);
    const int o = (r / 512) & 7;
    const int pos = r & 511;
    const int l = pos >> 3, j = pos & 7;
    const int n = 512 + t * 16 + (l & 15);
    const float w = Whh[n * HH + o * 32 + (l >> 4) * 8 + j];
    ushort hi = bf16_rne(w);
    ushort lo = bf16_rne(w - bf16_f32(hi));
    g_Whnp[((t * 8 + o) * 2) * 512 + pos] = hi;
    g_Whnp[((t * 8 + o) * 2 + 1) * 512 + pos] = lo;
  } else {  // Win (hi only)
    const int r = s - S4;
    const int t = r / (2 * 512);
    const int o = (r / 512) & 1;
    const int pos = r & 511;
    const int l = pos >> 3, j = pos & 7;
    const int n = 512 + t * 16 + (l & 15);
    const float w = Wih[n * DD + o * 32 + (l >> 4) * 8 + j];
    g_Winp[(t * 2 + o) * 512 + pos] = bf16_rne(w);
  }
}

#define MFMA(A, B, C) __builtin_amdgcn_mfma_f32_16x16x32_bf16((A), (B), (C), 0, 0, 0)

// LDS-only barrier: all inter-wave communication is via LDS, so wait lgkm only.
// Keeps weight global_loads (vmcnt) in flight across stage boundaries.
#define LBAR() asm volatile("s_waitcnt lgkmcnt(0)\ns_barrier" ::: "memory")

// 1 N-tile, K=256, 3-term split accumulation. A from bf16 hi/lo LDS planes.
__device__ __forceinline__ f32x4 mm1(const ushort* __restrict__ Ahi,
                                     const ushort* __restrict__ Alo,
                                     const ushort* __restrict__ pack,
                                     int tile, int lane, f32x4 acc)
{
  const int aoff = (lane & 15) * SB + (lane >> 4) * 8;
  const ushort* wp = pack + (size_t)tile * 8192 + lane * 8;
#pragma unroll
  for (int o = 0; o < 8; ++o) {
    const bf16x8 ah = *(const bf16x8*)(Ahi + aoff + o * 32);
    const bf16x8 al = *(const bf16x8*)(Alo + aoff + o * 32);
    const bf16x8 wh = *(const bf16x8*)(wp + o * 1024);
    const bf16x8 wl = *(const bf16x8*)(wp + o * 1024 + 512);
    acc = MFMA(ah, wh, acc);
    acc = MFMA(al, wh, acc);
    acc = MFMA(ah, wl, acc);
  }
  return acc;
}

// GRU r,z: tiles wv (r) and 16+wv (z) of Wrzp; K=256 h-part (3-term) + K=64 x-part (2-term)
__device__ __forceinline__ void mm_rz(const ushort* __restrict__ Ahi,
                                      const ushort* __restrict__ Alo,
                                      const ushort* __restrict__ Xhi,
                                      const ushort* __restrict__ Xlo,
                                      int wv, int lane, f32x4& ar, f32x4& az)
{
  const int aoff = (lane & 15) * SB + (lane >> 4) * 8;
  const int xoff = (lane & 15) * SXB + (lane >> 4) * 8;
  const ushort* pr = g_Wrzp + (size_t)wv * 10240 + lane * 8;
  const ushort* pz = g_Wrzp + (size_t)(16 + wv) * 10240 + lane * 8;
#pragma unroll
  for (int o = 0; o < 8; ++o) {
    const bf16x8 ah = *(const bf16x8*)(Ahi + aoff + o * 32);
    const bf16x8 al = *(const bf16x8*)(Alo + aoff + o * 32);
    const bf16x8 wrh = *(const bf16x8*)(pr + o * 1024);
    const bf16x8 wrl = *(const bf16x8*)(pr + o * 1024 + 512);
    const bf16x8 wzh = *(const bf16x8*)(pz + o * 1024);
    const bf16x8 wzl = *(const bf16x8*)(pz + o * 1024 + 512);
    ar = MFMA(ah, wrh, ar); az = MFMA(ah, wzh, az);
    ar = MFMA(al, wrh, ar); az = MFMA(al, wzh, az);
    ar = MFMA(ah, wrl, ar); az = MFMA(ah, wzl, az);
  }
#pragma unroll
  for (int o = 0; o < 2; ++o) {
    const bf16x8 xh = *(const bf16x8*)(Xhi + xoff + o * 32);
    const bf16x8 xl = *(const bf16x8*)(Xlo + xoff + o * 32);
    const bf16x8 wrh = *(const bf16x8*)(pr + (8 + o) * 1024);
    const bf16x8 wzh = *(const bf16x8*)(pz + (8 + o) * 1024);
    ar = MFMA(xh, wrh, ar); az = MFMA(xh, wzh, az);
    ar = MFMA(xl, wrh, ar); az = MFMA(xl, wzh, az);
  }
}

// GRU n-gate x-side: tile wv of Winp, K=64, hi-only weights, 2-term
__device__ __forceinline__ f32x4 mm_in(const ushort* __restrict__ Xhi,
                                       const ushort* __restrict__ Xlo,
                                       int wv, int lane, f32x4 acc)
{
  const int xoff = (lane & 15) * SXB + (lane >> 4) * 8;
  const ushort* pw = g_Winp + (size_t)wv * 1024 + lane * 8;
#pragma unroll
  for (int o = 0; o < 2; ++o) {
    const bf16x8 xh = *(const bf16x8*)(Xhi + xoff + o * 32);
    const bf16x8 xl = *(const bf16x8*)(Xlo + xoff + o * 32);
    const bf16x8 w = *(const bf16x8*)(pw + o * 512);
    acc = MFMA(xh, w, acc);
    acc = MFMA(xl, w, acc);
  }
  return acc;
}

__global__ __launch_bounds__(NTHR) void odegru_kernel(
    const float* __restrict__ x, const float* __restrict__ times,
    const float* __restrict__ mask,
    const float* __restrict__ b1, const float* __restrict__ b2,
    const float* __restrict__ bih, const float* __restrict__ bhh,
    float* __restrict__ out)
{
  // f32 state
  __shared__ __align__(16) float sAh[BB * SA];    // h (full f32 state)
  __shared__ __align__(16) float sAin[BB * SA];   // h_ode / RK stage input (f32, for epilogues)
  // bf16 hi/lo matmul planes
  __shared__ __align__(16) ushort sAhh[BB * SB], sAhl[BB * SB];
  __shared__ __align__(16) ushort sAinh[BB * SB], sAinl[BB * SB];
  __shared__ __align__(16) ushort sUh[BB * SB], sUl[BB * SB];
  __shared__ __align__(16) ushort sXh[BB * SXB], sXl[BB * SXB];
  __shared__ __align__(16) float sM[BB * TT_];    // mask rows for this block

  const int tid = threadIdx.x;
  const int lane = tid & 63;
  const int wv = tid >> 6;     // wave 0..15, owns output col-tile wv
  const int l15 = lane & 15;
  const int lq = lane >> 4;    // 0..3
  const int b0 = blockIdx.x * BB;

  const int c = wv * 16 + l15;       // this thread's output column
  const float b1c = b1[c];
  const float b2c = b2[c];
  const float brz_r = bih[c] + bhh[c];
  const float brz_z = bih[c + 256] + bhh[c + 256];
  const float bn_i = bih[c + 512];
  const float bn_h = bhh[c + 512];

  const f32x4 Z = {0.f, 0.f, 0.f, 0.f};

  // stage mask rows once
  sM[tid] = mask[(size_t)b0 * TT_ + tid];
  sM[tid + 1024] = mask[(size_t)b0 * TT_ + tid + 1024];

  // feval: A-planes -> kv (per-thread: col c, batches lq*4+q)
  auto feval = [&](const ushort* Ahi, const ushort* Alo, f32x4& kv) {
    f32x4 a = mm1(Ahi, Alo, g_W1p, wv, lane, Z);
#pragma unroll
    for (int q = 0; q < 4; ++q) {
      const int b = lq * 4 + q;
      const float u = fmaxf(a[q] + b1c, 0.f);
      ushort hi, lo; hl_split(u, hi, lo);
      sUh[b * SB + c] = hi;
      sUl[b * SB + c] = lo;
    }
    LBAR();
    f32x4 p = mm1(sUh, sUl, g_W2p, wv, lane, Z);
    kv = p + b2c;
  };

  // sAin <- sAh + coef*v (f32) and refresh Ain planes
  auto wAin = [&](float coef, const f32x4& v) {
#pragma unroll
    for (int q = 0; q < 4; ++q) {
      const int b = lq * 4 + q;
      const float nv = sAh[b * SA + c] + coef * v[q];
      sAin[b * SA + c] = nv;
      ushort hi, lo; hl_split(nv, hi, lo);
      sAinh[b * SB + c] = hi;
      sAinl[b * SB + c] = lo;
    }
  };

  for (int t = 0; t < TT_; ++t) {
    // stage x[:, t, :] as hi/lo planes
    {
      const int b = tid >> 6, d = tid & 63;
      const float v = x[((size_t)(b0 + b) * TT_ + t) * DD + d];
      ushort hi, lo; hl_split(v, hi, lo);
      sXh[b * SXB + d] = hi;
      sXl[b * SXB + d] = lo;
    }
    if (t == 0) {
      const int cc = tid & 255;
#pragma unroll
      for (int q = 0; q < 4; ++q) {
        const int b = (tid >> 8) * 4 + q;
        sAin[b * SA + cc] = 0.f;
        sAinh[b * SB + cc] = 0;
        sAinl[b * SB + cc] = 0;
      }
    }
    LBAR();

    if (t > 0) {
      const float dtv = times[t] - times[t - 1];
      f32x4 kv, ks;
      // k1 (reads h planes)
      feval(sAhh, sAhl, kv);
      ks = kv;
      wAin(0.5f * dtv, kv);
      LBAR();
      // k2
      feval(sAinh, sAinl, kv);
      ks += 2.0f * kv;
      wAin(0.5f * dtv, kv);
      LBAR();
      // k3
      feval(sAinh, sAinl, kv);
      ks += 2.0f * kv;
      wAin(dtv, kv);
      LBAR();
      // k4
      feval(sAinh, sAinl, kv);
      ks += kv;
      wAin(dtv * (1.0f / 6.0f), ks);  // sAin <- h_ode
      LBAR();
    }

    // ---- GRU: this wave computes r,z,hn,in for its 16 cols, all 16 batches ----
    {
      f32x4 ar = Z, az = Z;
      mm_rz(sAinh, sAinl, sXh, sXl, wv, lane, ar, az);
      f32x4 ahn = mm1(sAinh, sAinl, g_Whnp, wv, lane, Z);
      f32x4 ain = mm_in(sXh, sXl, wv, lane, Z);

#pragma unroll
      for (int q = 0; q < 4; ++q) {
        const int b = lq * 4 + q;
        const float gr = ar[q] + brz_r;
        const float gz = az[q] + brz_z;
        const float hn = ahn[q] + bn_h;
        const float gn = ain[q] + bn_i;
        const float hode = sAin[b * SA + c];
        const float rg = 1.f / (1.f + __expf(-gr));
        const float zg = 1.f / (1.f + __expf(-gz));
        const float ng = 1.f - 2.f / (__expf(2.f * (gn + rg * hn)) + 1.f);
        const float hnext = (1.f - zg) * ng + zg * hode;
        const float m = sM[b * TT_ + t];
        const float hnew = m * hnext + (1.f - m) * hode;
        out[((size_t)(b0 + b) * TT_ + t) * HH + c] = hnew;
        sAh[b * SA + c] = hnew;
        ushort hi, lo; hl_split(hnew, hi, lo);
        sAhh[b * SB + c] = hi;
        sAhl[b * SB + c] = lo;
      }
    }
    LBAR();
  }
}

extern "C" void kernel_launch(void* const* d_in, const int* in_sizes, int n_in,
                              void* d_out, int out_size, void* d_ws, size_t ws_size,
                              hipStream_t stream) {
  (void)in_sizes; (void)n_in; (void)d_ws; (void)ws_size; (void)out_size;
  const float* x     = (const float*)d_in[0];
  const float* times = (const float*)d_in[1];
  const float* mask  = (const float*)d_in[2];
  const float* W1    = (const float*)d_in[3];
  const float* b1    = (const float*)d_in[4];
  const float* W2    = (const float*)d_in[5];
  const float* b2    = (const float*)d_in[6];
  const float* Wih   = (const float*)d_in[7];
  const float* bih   = (const float*)d_in[8];
  const float* Whh   = (const float*)d_in[9];
  const float* bhh   = (const float*)d_in[10];
  float* out = (float*)d_out;

  hipLaunchKernelGGL(prep, dim3((376832 + 255) / 256), dim3(256), 0, stream,
                     W1, W2, Wih, Whh);
  hipLaunchKernelGGL(odegru_kernel, dim3(NBLK), dim3(NTHR), 0, stream,
                     x, times, mask, b1, b2, bih, bhh, out);
}